// Round 1
// baseline (280.128 us; speedup 1.0000x reference)
//
#include <hip/hip_runtime.h>

// Problem constants (fixed by setup_inputs in the reference)
constexpr int BS    = 2;
constexpr int A     = 900;
constexpr int P     = 13;
constexpr int NCAM  = 6;
constexpr int NLVL  = 4;
constexpr int NGRP  = 8;
constexpr int C     = 256;
constexpr int K     = 89760;                 // sum of H*W over 6 cams x 4 levels
constexpr int NSAMP = P * NCAM * NLVL;       // 312 (p, cam, lvl) combos
constexpr int NCORN = NSAMP * 4;             // 1248 bilinear corners
constexpr int AWN   = NSAMP * NGRP;          // 2496 attention weights per (b,a)

__global__ __launch_bounds__(256, 2) void dfa_kernel(
    const float* __restrict__ value,   // [BS][K][C]
    const int*   __restrict__ shapes,  // [NCAM][NLVL][2] (H, W)
    const int*   __restrict__ starts,  // [NCAM][NLVL]
    const float* __restrict__ locs,    // [BS][A][P][NCAM][2]
    const float* __restrict__ aw,      // [BS][A][P][NCAM][NLVL][NGRP]
    float*       __restrict__ out)     // [BS][A][C]
{
    __shared__ int   idx_s[NCORN];
    __shared__ float wgt_s[NCORN];
    __shared__ float aw_s[AWN];

    const int ba  = blockIdx.x;        // b * A + a
    const int tid = threadIdx.x;       // channel index 0..255
    const int b   = ba / A;

    // ---- Phase 1: cooperatively build sample metadata in LDS ----
    for (int t = tid; t < NSAMP; t += 256) {
        const int p   = t / (NCAM * NLVL);
        const int rem = t - p * (NCAM * NLVL);
        const int cam = rem >> 2;      // NLVL == 4
        const int lvl = rem & 3;

        const size_t lbase = ((((size_t)ba) * P + p) * NCAM + cam) * 2;
        const float lx = locs[lbase + 0];
        const float ly = locs[lbase + 1];

        const int H  = shapes[(cam * NLVL + lvl) * 2 + 0];
        const int W  = shapes[(cam * NLVL + lvl) * 2 + 1];
        const int st = starts[cam * NLVL + lvl];

        const float x = lx * (float)W - 0.5f;
        const float y = ly * (float)H - 0.5f;
        const float x0f = floorf(x), y0f = floorf(y);
        const float dx = x - x0f,   dy = y - y0f;
        const int   x0 = (int)x0f,  y0 = (int)y0f;

#pragma unroll
        for (int corner = 0; corner < 4; ++corner) {
            const int oy = corner >> 1, ox = corner & 1;
            const int yi = y0 + oy, xi = x0 + ox;
            float w = (oy ? dy : 1.0f - dy) * (ox ? dx : 1.0f - dx);
            const bool valid = (yi >= 0) & (yi < H) & (xi >= 0) & (xi < W);
            if (!valid) w = 0.0f;
            const int yc = min(max(yi, 0), H - 1);
            const int xc = min(max(xi, 0), W - 1);
            idx_s[t * 4 + corner] = st + yc * W + xc;
            wgt_s[t * 4 + corner] = w;
        }
    }

    // attention weights for this (b,a): 2496 contiguous floats, coalesced
    const size_t aw_base = (size_t)ba * AWN;
    for (int i = tid; i < AWN; i += 256) aw_s[i] = aw[aw_base + i];

    __syncthreads();

    // ---- Phase 2: gather + accumulate (one channel per thread) ----
    const int g = tid >> 5;                         // group = channel / 32
    const float* __restrict__ vbase = value + (size_t)b * K * C + tid;

    float acc = 0.0f;
#pragma unroll 2
    for (int s = 0; s < NSAMP; ++s) {
        const float w0 = wgt_s[s * 4 + 0];
        const float w1 = wgt_s[s * 4 + 1];
        const float w2 = wgt_s[s * 4 + 2];
        const float w3 = wgt_s[s * 4 + 3];
        const int   i0 = idx_s[s * 4 + 0];
        const int   i1 = idx_s[s * 4 + 1];
        const int   i2 = idx_s[s * 4 + 2];
        const int   i3 = idx_s[s * 4 + 3];

        const float v0 = vbase[(size_t)i0 * C];
        const float v1 = vbase[(size_t)i1 * C];
        const float v2 = vbase[(size_t)i2 * C];
        const float v3 = vbase[(size_t)i3 * C];

        float tmp = w0 * v0;
        tmp = fmaf(w1, v1, tmp);
        tmp = fmaf(w2, v2, tmp);
        tmp = fmaf(w3, v3, tmp);
        acc = fmaf(tmp, aw_s[s * NGRP + g], acc);
    }

    out[(size_t)ba * C + tid] = acc;
}

extern "C" void kernel_launch(void* const* d_in, const int* in_sizes, int n_in,
                              void* d_out, int out_size, void* d_ws, size_t ws_size,
                              hipStream_t stream) {
    const float* value  = (const float*)d_in[0];
    const int*   shapes = (const int*)d_in[1];
    const int*   starts = (const int*)d_in[2];
    const float* locs   = (const float*)d_in[3];
    const float* aw     = (const float*)d_in[4];
    float*       out    = (float*)d_out;

    dim3 grid(BS * A);
    dim3 block(256);
    dfa_kernel<<<grid, block, 0, stream>>>(value, shapes, starts, locs, aw, out);
}

// Round 2
// 249.414 us; speedup vs baseline: 1.1231x; 1.1231x over previous
//
#include <hip/hip_runtime.h>

// Problem constants (fixed by setup_inputs in the reference)
constexpr int BS    = 2;
constexpr int A     = 900;
constexpr int P     = 13;
constexpr int NCAM  = 6;
constexpr int NLVL  = 4;
constexpr int NGRP  = 8;
constexpr int C     = 256;
constexpr int K     = 89760;                 // sum of H*W over 6 cams x 4 levels
constexpr int NSAMP = P * NCAM * NLVL;       // 312 (p, cam, lvl) combos
constexpr int NCORN = NSAMP * 4;             // 1248 bilinear corners
constexpr int AWN   = NSAMP * NGRP;          // 2496 attention weights per (b,a)
constexpr int SPW   = NSAMP / 4;             // 78 samples per wave

__global__ __launch_bounds__(256, 2) void dfa_kernel(
    const float* __restrict__ value,   // [BS][K][C]
    const int*   __restrict__ shapes,  // [NCAM][NLVL][2] (H, W)
    const int*   __restrict__ starts,  // [NCAM][NLVL]
    const float* __restrict__ locs,    // [BS][A][P][NCAM][2]
    const float* __restrict__ aw,      // [BS][A][P][NCAM][NLVL][NGRP]
    float*       __restrict__ out)     // [BS][A][C]
{
    __shared__ int    idx_s[NCORN];
    __shared__ float  wgt_s[NCORN];
    __shared__ float  aw_s[AWN];
    __shared__ float4 red_s[3][64];

    const int ba  = blockIdx.x;        // b * A + a
    const int tid = threadIdx.x;
    const int b   = ba / A;

    // ---- Phase 1: cooperatively build sample metadata in LDS ----
    for (int t = tid; t < NSAMP; t += 256) {
        const int p   = t / (NCAM * NLVL);
        const int rem = t - p * (NCAM * NLVL);
        const int cam = rem >> 2;      // NLVL == 4
        const int lvl = rem & 3;

        const size_t lbase = ((((size_t)ba) * P + p) * NCAM + cam) * 2;
        const float lx = locs[lbase + 0];
        const float ly = locs[lbase + 1];

        const int H  = shapes[(cam * NLVL + lvl) * 2 + 0];
        const int W  = shapes[(cam * NLVL + lvl) * 2 + 1];
        const int st = starts[cam * NLVL + lvl];

        const float x = lx * (float)W - 0.5f;
        const float y = ly * (float)H - 0.5f;
        const float x0f = floorf(x), y0f = floorf(y);
        const float dx = x - x0f,   dy = y - y0f;
        const int   x0 = (int)x0f,  y0 = (int)y0f;

#pragma unroll
        for (int corner = 0; corner < 4; ++corner) {
            const int oy = corner >> 1, ox = corner & 1;
            const int yi = y0 + oy, xi = x0 + ox;
            float w = (oy ? dy : 1.0f - dy) * (ox ? dx : 1.0f - dx);
            const bool valid = (yi >= 0) & (yi < H) & (xi >= 0) & (xi < W);
            if (!valid) w = 0.0f;
            const int yc = min(max(yi, 0), H - 1);
            const int xc = min(max(xi, 0), W - 1);
            idx_s[t * 4 + corner] = st + yc * W + xc;
            wgt_s[t * 4 + corner] = w;
        }
    }

    // attention weights for this (b,a): 2496 contiguous floats, coalesced
    const size_t aw_base = (size_t)ba * AWN;
    for (int i = tid; i < AWN; i += 256) aw_s[i] = aw[aw_base + i];

    __syncthreads();

    // ---- Phase 2: float4 gather, samples split across the 4 waves ----
    const int wid  = tid >> 6;         // wave id 0..3
    const int lane = tid & 63;         // lane -> channels [lane*4, lane*4+4)
    const int g    = lane >> 3;        // group = (lane*4)/32

    const float* __restrict__ vbase = value + (size_t)b * K * C + lane * 4;

    float4 acc = {0.0f, 0.0f, 0.0f, 0.0f};

    const int s_end = (wid + 1) * SPW;
#pragma unroll 2
    for (int s = wid * SPW; s < s_end; ++s) {
        const float w0 = wgt_s[s * 4 + 0];
        const float w1 = wgt_s[s * 4 + 1];
        const float w2 = wgt_s[s * 4 + 2];
        const float w3 = wgt_s[s * 4 + 3];
        const int   i0 = idx_s[s * 4 + 0];
        const int   i1 = idx_s[s * 4 + 1];
        const int   i2 = idx_s[s * 4 + 2];
        const int   i3 = idx_s[s * 4 + 3];

        const float4 v0 = *reinterpret_cast<const float4*>(vbase + (size_t)i0 * C);
        const float4 v1 = *reinterpret_cast<const float4*>(vbase + (size_t)i1 * C);
        const float4 v2 = *reinterpret_cast<const float4*>(vbase + (size_t)i2 * C);
        const float4 v3 = *reinterpret_cast<const float4*>(vbase + (size_t)i3 * C);

        const float wa = aw_s[s * NGRP + g];

        float4 t;
        t.x = w0 * v0.x; t.y = w0 * v0.y; t.z = w0 * v0.z; t.w = w0 * v0.w;
        t.x = fmaf(w1, v1.x, t.x); t.y = fmaf(w1, v1.y, t.y);
        t.z = fmaf(w1, v1.z, t.z); t.w = fmaf(w1, v1.w, t.w);
        t.x = fmaf(w2, v2.x, t.x); t.y = fmaf(w2, v2.y, t.y);
        t.z = fmaf(w2, v2.z, t.z); t.w = fmaf(w2, v2.w, t.w);
        t.x = fmaf(w3, v3.x, t.x); t.y = fmaf(w3, v3.y, t.y);
        t.z = fmaf(w3, v3.z, t.z); t.w = fmaf(w3, v3.w, t.w);

        acc.x = fmaf(t.x, wa, acc.x);
        acc.y = fmaf(t.y, wa, acc.y);
        acc.z = fmaf(t.z, wa, acc.z);
        acc.w = fmaf(t.w, wa, acc.w);
    }

    // ---- Phase 3: cross-wave reduction of the 4 partial accumulators ----
    if (wid > 0) red_s[wid - 1][lane] = acc;
    __syncthreads();

    if (wid == 0) {
        const float4 r0 = red_s[0][lane];
        const float4 r1 = red_s[1][lane];
        const float4 r2 = red_s[2][lane];
        acc.x += r0.x + r1.x + r2.x;
        acc.y += r0.y + r1.y + r2.y;
        acc.z += r0.z + r1.z + r2.z;
        acc.w += r0.w + r1.w + r2.w;
        *reinterpret_cast<float4*>(out + (size_t)ba * C + lane * 4) = acc;
    }
}

extern "C" void kernel_launch(void* const* d_in, const int* in_sizes, int n_in,
                              void* d_out, int out_size, void* d_ws, size_t ws_size,
                              hipStream_t stream) {
    const float* value  = (const float*)d_in[0];
    const int*   shapes = (const int*)d_in[1];
    const int*   starts = (const int*)d_in[2];
    const float* locs   = (const float*)d_in[3];
    const float* aw     = (const float*)d_in[4];
    float*       out    = (float*)d_out;

    dim3 grid(BS * A);
    dim3 block(256);
    dfa_kernel<<<grid, block, 0, stream>>>(value, shapes, starts, locs, aw, out);
}